// Round 5
// baseline (1150.579 us; speedup 1.0000x reference)
//
#include <hip/hip_runtime.h>
#include <math.h>

#define NN 10000
#define NFEAT 512
#define NHID 256
#define NCLASS 40
#define MAXDEG 64

typedef __attribute__((ext_vector_type(8))) short short8v;   // 8 bf16 (4 VGPR)
typedef __attribute__((ext_vector_type(4))) float floatx4;   // MFMA acc

static __device__ __forceinline__ unsigned short bf16_rne(float f) {
    unsigned u = __builtin_bit_cast(unsigned, f);
    u += 0x7fffu + ((u >> 16) & 1u);
    return (unsigned short)(u >> 16);
}
static __device__ __forceinline__ float bf16_f32(unsigned short h) {
    unsigned u = ((unsigned)h) << 16;
    return __builtin_bit_cast(float, u);
}

// ---------------------------------------------------------------------------
// build_adj: one WAVE per row; ballot-compaction. HBM-BW bound (400 MB scan).
// No min-waves clamp: 8-VGPR kernel -> full occupancy for latency hiding.
// ---------------------------------------------------------------------------
__global__ __launch_bounds__(256) void build_adj(const float* __restrict__ A,
                                                 int* __restrict__ cols,
                                                 int* __restrict__ deg,
                                                 float* __restrict__ dinv) {
    int wave = threadIdx.x >> 6;
    int lane = threadIdx.x & 63;
    int row = blockIdx.x * 4 + wave;
    if (row >= NN) return;
    const float4* Arow = (const float4*)(A + (size_t)row * NN);
    int* crow = cols + (size_t)row * MAXDEG;
    int off = 0;
    unsigned long long lmask = (lane == 63) ? 0xFFFFFFFFFFFFFFFFull >> 1
                                            : ((1ull << lane) - 1ull);
    for (int q = lane; q < NN / 4; q += 64) {
        float4 v = Arow[q];
        unsigned long long b0 = __ballot(v.x != 0.f);
        unsigned long long b1 = __ballot(v.y != 0.f);
        unsigned long long b2 = __ballot(v.z != 0.f);
        unsigned long long b3 = __ballot(v.w != 0.f);
        if (v.x != 0.f) { int p = off + __popcll(b0 & lmask); if (p < MAXDEG) crow[p] = 4 * q + 0; }
        off += __popcll(b0);
        if (v.y != 0.f) { int p = off + __popcll(b1 & lmask); if (p < MAXDEG) crow[p] = 4 * q + 1; }
        off += __popcll(b1);
        if (v.z != 0.f) { int p = off + __popcll(b2 & lmask); if (p < MAXDEG) crow[p] = 4 * q + 2; }
        off += __popcll(b2);
        if (v.w != 0.f) { int p = off + __popcll(b3 & lmask); if (p < MAXDEG) crow[p] = 4 * q + 3; }
        off += __popcll(b3);
    }
    if (lane == 0) {
        int d = off < MAXDEG ? off : MAXDEG;
        deg[row] = d;
        dinv[row] = 1.0f / sqrtf((float)(off + 1));
    }
}

// ---------------------------------------------------------------------------
// split_f32: v -> bf16 hi + bf16 lo (residual), 4 elems/thread
// ---------------------------------------------------------------------------
__global__ __launch_bounds__(256) void split_f32(const float* __restrict__ src,
                                                 unsigned short* __restrict__ hi,
                                                 unsigned short* __restrict__ lo,
                                                 int n4) {
    int i = blockIdx.x * 256 + threadIdx.x;
    if (i >= n4) return;
    float4 v = ((const float4*)src)[i];
    ushort4 h, l;
    h.x = bf16_rne(v.x); l.x = bf16_rne(v.x - bf16_f32(h.x));
    h.y = bf16_rne(v.y); l.y = bf16_rne(v.y - bf16_f32(h.y));
    h.z = bf16_rne(v.z); l.z = bf16_rne(v.z - bf16_f32(h.z));
    h.w = bf16_rne(v.w); l.w = bf16_rne(v.w - bf16_f32(h.w));
    ((ushort4*)hi)[i] = h;
    ((ushort4*)lo)[i] = l;
}

// ---------------------------------------------------------------------------
// Pack B operands into MFMA B-fragment order:
//   P[((ks*CT + ct)*64 + lane)*8 + j] = B[k][c],
//   k = ks*32 + 8*(lane>>4) + j,  c = ct*16 + (lane&15)
// ---------------------------------------------------------------------------
__global__ __launch_bounds__(256) void pack_layer(const float* __restrict__ W,
                                                  unsigned short* __restrict__ Ph,
                                                  unsigned short* __restrict__ Pl) {
    int idx = blockIdx.x * 256 + threadIdx.x;       // K*N = 256*256
    if (idx >= 256 * 256) return;
    int j = idx & 7, lane = (idx >> 3) & 63;
    int ctks = idx >> 9;                            // ks*16 + ct
    int ct = ctks & 15, ks = ctks >> 4;
    int k = ks * 32 + ((lane >> 4) << 3) + j;
    int c = ct * 16 + (lane & 15);
    float w = 0.25f * (W[k * NHID + c] + W[c * NHID + k]);   // step*0.5*(W+W^T)
    unsigned short h = bf16_rne(w);
    Ph[idx] = h;
    Pl[idx] = bf16_rne(w - bf16_f32(h));
}

__global__ __launch_bounds__(256) void pack_enc(const float* __restrict__ EW,
                                                unsigned short* __restrict__ Ph,
                                                unsigned short* __restrict__ Pl) {
    int idx = blockIdx.x * 256 + threadIdx.x;       // K*N = 512*256
    if (idx >= 512 * 256) return;
    int j = idx & 7, lane = (idx >> 3) & 63;
    int ctks = idx >> 9;                            // ks*16 + ct  (16 ks, 16 ct)
    int ct = ctks & 15, ks = ctks >> 4;
    int k = ks * 32 + ((lane >> 4) << 3) + j;
    int c = ct * 16 + (lane & 15);                  // c == h (output unit)
    float w = EW[c * NFEAT + k];                    // B[k][h] = enc_w[h][k]
    unsigned short h = bf16_rne(w);
    Ph[idx] = h;
    Pl[idx] = bf16_rne(w - bf16_f32(h));
}

__global__ __launch_bounds__(256) void pack_dec(const float* __restrict__ DW,
                                                unsigned short* __restrict__ Ph,
                                                unsigned short* __restrict__ Pl) {
    int idx = blockIdx.x * 256 + threadIdx.x;       // K*Npad = 256*48
    if (idx >= 256 * 48) return;
    int j = idx & 7, lane = (idx >> 3) & 63;
    int ctks = idx >> 9;                            // 0..23 : ks*3 + ct
    int ct = ctks % 3, ks = ctks / 3;
    int k = ks * 32 + ((lane >> 4) << 3) + j;
    int c = ct * 16 + (lane & 15);
    float w = (c < NCLASS) ? DW[c * NHID + k] : 0.f; // B[k][c] = dec_w[c][k]
    unsigned short h = bf16_rne(w);
    Ph[idx] = h;
    Pl[idx] = bf16_rne(w - bf16_f32(h));
}

// ---------------------------------------------------------------------------
// MFMA GEMM (bf16x3 split emulating f32): out = A*B [+epilogue]
// A: [M,K] as bf16 hi/lo row-major.  B: packed fragments (see pack_*).
// Block = 256 thr = 4 waves; wave computes 16 rows x NT*16 cols; K unrolled.
// EPI: 0 = enc (relu(+bias)), 1 = layer (x + relu(x+acc), opt. split-out),
//      2 = dec (+bias, col guard NCLASS)
// ---------------------------------------------------------------------------
template <int K, int NTOT, int NT, int EPI>
__global__ __launch_bounds__(256) void mfma_gemm(const unsigned short* __restrict__ Ah,
                                                 const unsigned short* __restrict__ Al,
                                                 const unsigned short* __restrict__ Ph,
                                                 const unsigned short* __restrict__ Pl,
                                                 const float* __restrict__ aux,
                                                 float* __restrict__ out,
                                                 unsigned short* __restrict__ oh,
                                                 unsigned short* __restrict__ ol,
                                                 int wsplit) {
    int tid = threadIdx.x;
    int wave = tid >> 6, lane = tid & 63;
    int rowA = blockIdx.x * 64 + wave * 16 + (lane & 15);
    if (rowA >= NN) rowA = NN - 1;                  // clamped loads, guarded stores
    int ct0 = blockIdx.y * NT;
    int koff = (lane >> 4) << 3;

    floatx4 acc[NT];
#pragma unroll
    for (int t = 0; t < NT; ++t) acc[t] = (floatx4){0.f, 0.f, 0.f, 0.f};

#pragma unroll
    for (int ks = 0; ks < K / 32; ++ks) {
        short8v a_h = *(const short8v*)(Ah + (size_t)rowA * K + ks * 32 + koff);
        short8v a_l = *(const short8v*)(Al + (size_t)rowA * K + ks * 32 + koff);
        const unsigned short* bph = Ph + ((size_t)(ks * NTOT + ct0) * 64 + lane) * 8;
        const unsigned short* bpl = Pl + ((size_t)(ks * NTOT + ct0) * 64 + lane) * 8;
#pragma unroll
        for (int t = 0; t < NT; ++t) {
            short8v b_h = *(const short8v*)(bph + t * 512);
            short8v b_l = *(const short8v*)(bpl + t * 512);
            acc[t] = __builtin_amdgcn_mfma_f32_16x16x32_bf16(a_h, b_h, acc[t], 0, 0, 0);
            acc[t] = __builtin_amdgcn_mfma_f32_16x16x32_bf16(a_l, b_h, acc[t], 0, 0, 0);
            acc[t] = __builtin_amdgcn_mfma_f32_16x16x32_bf16(a_h, b_l, acc[t], 0, 0, 0);
        }
    }

    // D layout: col = lane&15, row = 4*(lane>>4) + reg   [m89-verified]
    int rbase = blockIdx.x * 64 + wave * 16 + ((lane >> 4) << 2);
    int cbase = ct0 * 16 + (lane & 15);
#pragma unroll
    for (int t = 0; t < NT; ++t) {
        int c = cbase + t * 16;
#pragma unroll
        for (int i = 0; i < 4; ++i) {
            int r = rbase + i;
            if (r < NN) {
                float v = acc[t][i];
                if (EPI == 0) {
                    out[(size_t)r * (NTOT * 16) + c] = fmaxf(v + aux[c], 0.f);
                } else if (EPI == 1) {
                    float xv = aux[(size_t)r * NHID + c];
                    float o = xv + fmaxf(xv + v, 0.f);
                    out[(size_t)r * NHID + c] = o;
                    if (wsplit) {
                        unsigned short h = bf16_rne(o);
                        oh[(size_t)r * NHID + c] = h;
                        ol[(size_t)r * NHID + c] = bf16_rne(o - bf16_f32(h));
                    }
                } else {
                    if (c < NCLASS) out[(size_t)r * NCLASS + c] = v + aux[c];
                }
            }
        }
    }
}

// ---------------------------------------------------------------------------
// SpMM: Y[i] = dinv[i]*( dinv[i]*X[i] + sum_{j in N(i)} dinv[j]*X[j] )
// one wave per row; emits bf16 hi/lo split of Y (A-operand of layer GEMM)
// ---------------------------------------------------------------------------
__global__ __launch_bounds__(256) void spmm(const int* __restrict__ cols,
                                            const int* __restrict__ deg,
                                            const float* __restrict__ dinv,
                                            const float* __restrict__ X,
                                            unsigned short* __restrict__ Yh,
                                            unsigned short* __restrict__ Yl) {
    int wave = threadIdx.x >> 6;
    int lane = threadIdx.x & 63;
    int row = blockIdx.x * 4 + wave;
    if (row >= NN) return;
    int d = deg[row];
    float di = dinv[row];
    const int* crow = cols + (size_t)row * MAXDEG;
    const float4* Xv = (const float4*)X;
    float4 xs = Xv[(size_t)row * 64 + lane];
    float4 acc = make_float4(di * xs.x, di * xs.y, di * xs.z, di * xs.w);
    for (int j = 0; j < d; ++j) {
        int c = crow[j];
        float w = dinv[c];
        float4 xv = Xv[(size_t)c * 64 + lane];
        acc.x = fmaf(w, xv.x, acc.x);
        acc.y = fmaf(w, xv.y, acc.y);
        acc.z = fmaf(w, xv.z, acc.z);
        acc.w = fmaf(w, xv.w, acc.w);
    }
    float4 o = make_float4(di * acc.x, di * acc.y, di * acc.z, di * acc.w);
    ushort4 h, l;
    h.x = bf16_rne(o.x); l.x = bf16_rne(o.x - bf16_f32(h.x));
    h.y = bf16_rne(o.y); l.y = bf16_rne(o.y - bf16_f32(h.y));
    h.z = bf16_rne(o.z); l.z = bf16_rne(o.z - bf16_f32(h.z));
    h.w = bf16_rne(o.w); l.w = bf16_rne(o.w - bf16_f32(h.w));
    ((ushort4*)Yh)[(size_t)row * 64 + lane] = h;
    ((ushort4*)Yl)[(size_t)row * 64 + lane] = l;
}

// ---------------------------------------------------------------------------
// NOTE: this round is a controlled MEASUREMENT build — the exact round-2
// pipeline (measured 804 us) executed TWICE back-to-back (idempotent).
// K_kernels = dur_r5 - 804;  Fixed = 2*804 - dur_r5.
// ---------------------------------------------------------------------------
extern "C" void kernel_launch(void* const* d_in, const int* in_sizes, int n_in,
                              void* d_out, int out_size, void* d_ws, size_t ws_size,
                              hipStream_t stream) {
    const float* x      = (const float*)d_in[0];
    const float* A      = (const float*)d_in[1];
    const float* enc_w  = (const float*)d_in[2];
    const float* enc_b  = (const float*)d_in[3];
    const float* conv_w = (const float*)d_in[4];
    const float* dec_w  = (const float*)d_in[5];
    const float* dec_b  = (const float*)d_in[6];
    float* out = (float*)d_out;

    char* w = (char*)d_ws;
    auto alloc = [&](size_t bytes) {
        char* p = w;
        w += (bytes + 255) & ~(size_t)255;
        return p;
    };
    int*            cols = (int*)alloc((size_t)NN * MAXDEG * 4);
    int*            deg  = (int*)alloc((size_t)NN * 4);
    float*          dinv = (float*)alloc((size_t)NN * 4);
    unsigned short* xh   = (unsigned short*)alloc((size_t)NN * NFEAT * 2);
    unsigned short* xl   = (unsigned short*)alloc((size_t)NN * NFEAT * 2);
    unsigned short* PEh  = (unsigned short*)alloc((size_t)NFEAT * NHID * 2);
    unsigned short* PEl  = (unsigned short*)alloc((size_t)NFEAT * NHID * 2);
    unsigned short* PWh  = (unsigned short*)alloc((size_t)NHID * NHID * 2);
    unsigned short* PWl  = (unsigned short*)alloc((size_t)NHID * NHID * 2);
    unsigned short* PDh  = (unsigned short*)alloc((size_t)NHID * 48 * 2);
    unsigned short* PDl  = (unsigned short*)alloc((size_t)NHID * 48 * 2);
    float*          Xa   = (float*)alloc((size_t)NN * NHID * 4);
    float*          Xb   = (float*)alloc((size_t)NN * NHID * 4);
    unsigned short* Yh   = (unsigned short*)alloc((size_t)NN * NHID * 2);
    unsigned short* Yl   = (unsigned short*)alloc((size_t)NN * NHID * 2);
    unsigned short* Xfh  = (unsigned short*)alloc((size_t)NN * NHID * 2);
    unsigned short* Xfl  = (unsigned short*)alloc((size_t)NN * NHID * 2);

    for (int rep = 0; rep < 2; ++rep) {
        build_adj<<<(NN + 3) / 4, 256, 0, stream>>>(A, cols, deg, dinv);
        split_f32<<<(NN * NFEAT / 4 + 255) / 256, 256, 0, stream>>>(x, xh, xl, NN * NFEAT / 4);
        pack_enc<<<(NFEAT * NHID + 255) / 256, 256, 0, stream>>>(enc_w, PEh, PEl);
        pack_layer<<<(NHID * NHID + 255) / 256, 256, 0, stream>>>(conv_w, PWh, PWl);
        pack_dec<<<(NHID * 48 + 255) / 256, 256, 0, stream>>>(dec_w, PDh, PDl);

        dim3 g2((NN + 63) / 64, 2);
        // encoder: X = relu(x @ enc_w^T + b), K=512, N=256
        mfma_gemm<NFEAT, 16, 8, 0><<<g2, 256, 0, stream>>>(xh, xl, PEh, PEl, enc_b, Xa,
                                                           nullptr, nullptr, 0);
        float* Xcur = Xa;
        float* Xnxt = Xb;
        for (int layer = 0; layer < 4; ++layer) {
            spmm<<<(NN + 3) / 4, 256, 0, stream>>>(cols, deg, dinv, Xcur, Yh, Yl);
            mfma_gemm<NHID, 16, 8, 1><<<g2, 256, 0, stream>>>(Yh, Yl, PWh, PWl, Xcur, Xnxt,
                                                              Xfh, Xfl, layer == 3 ? 1 : 0);
            float* t = Xcur; Xcur = Xnxt; Xnxt = t;
        }
        dim3 g1((NN + 63) / 64, 1);
        mfma_gemm<NHID, 3, 3, 2><<<g1, 256, 0, stream>>>(Xfh, Xfl, PDh, PDl, dec_b, out,
                                                         nullptr, nullptr, 0);
    }
}

// Round 6
// 698.986 us; speedup vs baseline: 1.6461x; 1.6461x over previous
//
#include <hip/hip_runtime.h>
#include <math.h>

#define NN 10000
#define NFEAT 512
#define NHID 256
#define NCLASS 40
#define MAXDEG 64

typedef __attribute__((ext_vector_type(8))) short short8v;   // 8 bf16 (4 VGPR)
typedef __attribute__((ext_vector_type(4))) float floatx4;   // MFMA acc

static __device__ __forceinline__ unsigned short bf16_rne(float f) {
    unsigned u = __builtin_bit_cast(unsigned, f);
    u += 0x7fffu + ((u >> 16) & 1u);
    return (unsigned short)(u >> 16);
}
static __device__ __forceinline__ float bf16_f32(unsigned short h) {
    unsigned u = ((unsigned)h) << 16;
    return __builtin_bit_cast(float, u);
}

// ---------------------------------------------------------------------------
// prep: fused one-shot setup.
//   blocks [0,512)        : pack enc_w  -> PEh/PEl   (K=512, NTOT=16)
//   blocks [512,768)      : pack conv_w -> PWh/PWl   (K=256, NTOT=16)
//   blocks [768,816)      : pack dec_w  -> PDh/PDl   (K=256, NTOT=3, 48 cols)
//   blocks [816,5816)     : split x -> xh/xl (1 float4 / thread)
//   blocks [5816,5856)    : zero deg[]
// Pack layout: P[((ks*NTOT+ct)*64+lane)*8+j] = B[k][c],
//   k = ks*32 + 8*(lane>>4) + j,  c = ct*16 + (lane&15)
// ---------------------------------------------------------------------------
__global__ __launch_bounds__(256) void prep(const float* __restrict__ EW,
                                            const float* __restrict__ W,
                                            const float* __restrict__ DW,
                                            const float* __restrict__ x,
                                            unsigned short* __restrict__ PEh,
                                            unsigned short* __restrict__ PEl,
                                            unsigned short* __restrict__ PWh,
                                            unsigned short* __restrict__ PWl,
                                            unsigned short* __restrict__ PDh,
                                            unsigned short* __restrict__ PDl,
                                            unsigned short* __restrict__ xh,
                                            unsigned short* __restrict__ xl,
                                            int* __restrict__ deg) {
    int b = blockIdx.x;
    if (b < 512) {                                  // enc pack
        int idx = b * 256 + threadIdx.x;
        int j = idx & 7, lane = (idx >> 3) & 63;
        int ctks = idx >> 9;
        int ct = ctks & 15, ks = ctks >> 4;
        int k = ks * 32 + ((lane >> 4) << 3) + j;
        int c = ct * 16 + (lane & 15);
        float w = EW[(size_t)c * NFEAT + k];
        unsigned short h = bf16_rne(w);
        PEh[idx] = h;
        PEl[idx] = bf16_rne(w - bf16_f32(h));
    } else if (b < 768) {                           // layer pack (0.25*(W+W^T))
        int idx = (b - 512) * 256 + threadIdx.x;
        int j = idx & 7, lane = (idx >> 3) & 63;
        int ctks = idx >> 9;
        int ct = ctks & 15, ks = ctks >> 4;
        int k = ks * 32 + ((lane >> 4) << 3) + j;
        int c = ct * 16 + (lane & 15);
        float w = 0.25f * (W[k * NHID + c] + W[c * NHID + k]);
        unsigned short h = bf16_rne(w);
        PWh[idx] = h;
        PWl[idx] = bf16_rne(w - bf16_f32(h));
    } else if (b < 816) {                           // dec pack
        int idx = (b - 768) * 256 + threadIdx.x;    // 12288
        int j = idx & 7, lane = (idx >> 3) & 63;
        int ctks = idx >> 9;
        int ct = ctks % 3, ks = ctks / 3;
        int k = ks * 32 + ((lane >> 4) << 3) + j;
        int c = ct * 16 + (lane & 15);
        float w = (c < NCLASS) ? DW[(size_t)c * NHID + k] : 0.f;
        unsigned short h = bf16_rne(w);
        PDh[idx] = h;
        PDl[idx] = bf16_rne(w - bf16_f32(h));
    } else if (b < 5816) {                          // split x (f32 -> bf16 hi/lo)
        int i = (b - 816) * 256 + threadIdx.x;      // 1,280,000 float4
        float4 v = ((const float4*)x)[i];
        ushort4 h, l;
        h.x = bf16_rne(v.x); l.x = bf16_rne(v.x - bf16_f32(h.x));
        h.y = bf16_rne(v.y); l.y = bf16_rne(v.y - bf16_f32(h.y));
        h.z = bf16_rne(v.z); l.z = bf16_rne(v.z - bf16_f32(h.z));
        h.w = bf16_rne(v.w); l.w = bf16_rne(v.w - bf16_f32(h.w));
        ((ushort4*)xh)[i] = h;
        ((ushort4*)xl)[i] = l;
    } else {                                        // zero deg
        int i = (b - 5816) * 256 + threadIdx.x;
        if (i < NN) deg[i] = 0;
    }
}

// ---------------------------------------------------------------------------
// scan_upper: A is symmetric with zero diagonal -> scan only j > i (200 MB
// instead of 400), mirror each edge into both rows via atomic index
// reservation. Edge order in cols[] is arbitrary (sum order differs from
// reference by f32 rounding only).
// ---------------------------------------------------------------------------
__global__ __launch_bounds__(256) void scan_upper(const float* __restrict__ A,
                                                  int* __restrict__ cols,
                                                  int* __restrict__ deg) {
    int wave = threadIdx.x >> 6;
    int lane = threadIdx.x & 63;
    int row = blockIdx.x * 4 + wave;
    if (row >= NN) return;
    const float4* Arow = (const float4*)(A + (size_t)row * NN);
    int qstart = (row + 1) >> 2;                    // first float4 containing j>row
    for (int q = qstart + lane; q < NN / 4; q += 64) {
        float4 v = Arow[q];
        int jb = 4 * q;
        if (v.x != 0.f && jb + 0 > row) {
            int p = atomicAdd(&deg[row], 1); if (p < MAXDEG) cols[(size_t)row * MAXDEG + p] = jb;
            int m = atomicAdd(&deg[jb], 1);  if (m < MAXDEG) cols[(size_t)jb * MAXDEG + m] = row;
        }
        if (v.y != 0.f && jb + 1 > row) {
            int j = jb + 1;
            int p = atomicAdd(&deg[row], 1); if (p < MAXDEG) cols[(size_t)row * MAXDEG + p] = j;
            int m = atomicAdd(&deg[j], 1);   if (m < MAXDEG) cols[(size_t)j * MAXDEG + m] = row;
        }
        if (v.z != 0.f && jb + 2 > row) {
            int j = jb + 2;
            int p = atomicAdd(&deg[row], 1); if (p < MAXDEG) cols[(size_t)row * MAXDEG + p] = j;
            int m = atomicAdd(&deg[j], 1);   if (m < MAXDEG) cols[(size_t)j * MAXDEG + m] = row;
        }
        if (v.w != 0.f && jb + 3 > row) {
            int j = jb + 3;
            int p = atomicAdd(&deg[row], 1); if (p < MAXDEG) cols[(size_t)row * MAXDEG + p] = j;
            int m = atomicAdd(&deg[j], 1);   if (m < MAXDEG) cols[(size_t)j * MAXDEG + m] = row;
        }
    }
}

// finalize: dinv from full degree; clamp deg for the spmm loop.
__global__ __launch_bounds__(256) void finalize(int* __restrict__ deg,
                                                float* __restrict__ dinv) {
    int i = blockIdx.x * 256 + threadIdx.x;
    if (i >= NN) return;
    int d = deg[i];
    dinv[i] = 1.0f / sqrtf((float)(d + 1));
    deg[i] = d < MAXDEG ? d : MAXDEG;
}

// ---------------------------------------------------------------------------
// MFMA GEMM (bf16x3 split emulating f32): out = A*B [+epilogue]
// A: [M,K] as bf16 hi/lo row-major.  B: packed fragments (see prep).
// Block = 4 waves; wave computes 16 rows x NT*16 cols.
// EPI: 0 = enc (relu(+bias)), 1 = layer (x + relu(x+acc), opt. split-out),
//      2 = dec (+bias, col guard NCLASS)
// ---------------------------------------------------------------------------
template <int K, int NTOT, int NT, int EPI>
__global__ __launch_bounds__(256) void mfma_gemm(const unsigned short* __restrict__ Ah,
                                                 const unsigned short* __restrict__ Al,
                                                 const unsigned short* __restrict__ Ph,
                                                 const unsigned short* __restrict__ Pl,
                                                 const float* __restrict__ aux,
                                                 float* __restrict__ out,
                                                 unsigned short* __restrict__ oh,
                                                 unsigned short* __restrict__ ol,
                                                 int wsplit) {
    int tid = threadIdx.x;
    int wave = tid >> 6, lane = tid & 63;
    int rowA = blockIdx.x * 64 + wave * 16 + (lane & 15);
    if (rowA >= NN) rowA = NN - 1;                  // clamped loads, guarded stores
    int ct0 = blockIdx.y * NT;
    int koff = (lane >> 4) << 3;

    floatx4 acc[NT];
#pragma unroll
    for (int t = 0; t < NT; ++t) acc[t] = (floatx4){0.f, 0.f, 0.f, 0.f};

#pragma unroll
    for (int ks = 0; ks < K / 32; ++ks) {
        short8v a_h = *(const short8v*)(Ah + (size_t)rowA * K + ks * 32 + koff);
        short8v a_l = *(const short8v*)(Al + (size_t)rowA * K + ks * 32 + koff);
        const unsigned short* bph = Ph + ((size_t)(ks * NTOT + ct0) * 64 + lane) * 8;
        const unsigned short* bpl = Pl + ((size_t)(ks * NTOT + ct0) * 64 + lane) * 8;
#pragma unroll
        for (int t = 0; t < NT; ++t) {
            short8v b_h = *(const short8v*)(bph + t * 512);
            short8v b_l = *(const short8v*)(bpl + t * 512);
            acc[t] = __builtin_amdgcn_mfma_f32_16x16x32_bf16(a_h, b_h, acc[t], 0, 0, 0);
            acc[t] = __builtin_amdgcn_mfma_f32_16x16x32_bf16(a_l, b_h, acc[t], 0, 0, 0);
            acc[t] = __builtin_amdgcn_mfma_f32_16x16x32_bf16(a_h, b_l, acc[t], 0, 0, 0);
        }
    }

    // D layout: col = lane&15, row = 4*(lane>>4) + reg   [m89-verified]
    int rbase = blockIdx.x * 64 + wave * 16 + ((lane >> 4) << 2);
    int cbase = ct0 * 16 + (lane & 15);
#pragma unroll
    for (int t = 0; t < NT; ++t) {
        int c = cbase + t * 16;
#pragma unroll
        for (int i = 0; i < 4; ++i) {
            int r = rbase + i;
            if (r < NN) {
                float v = acc[t][i];
                if (EPI == 0) {
                    out[(size_t)r * NHID + c] = fmaxf(v + aux[c], 0.f);
                } else if (EPI == 1) {
                    float xv = aux[(size_t)r * NHID + c];
                    float o = xv + fmaxf(xv + v, 0.f);
                    out[(size_t)r * NHID + c] = o;
                    if (wsplit) {
                        unsigned short h = bf16_rne(o);
                        oh[(size_t)r * NHID + c] = h;
                        ol[(size_t)r * NHID + c] = bf16_rne(o - bf16_f32(h));
                    }
                } else {
                    if (c < NCLASS) out[(size_t)r * NCLASS + c] = v + aux[c];
                }
            }
        }
    }
}

// ---------------------------------------------------------------------------
// SpMM: Y[i] = dinv[i]*( dinv[i]*X[i] + sum_{j in N(i)} dinv[j]*X[j] )
// one wave per row; 2-way unrolled neighbor loop (independent accumulators)
// to overlap gather latency. Emits bf16 hi/lo split of Y.
// ---------------------------------------------------------------------------
__global__ __launch_bounds__(256) void spmm(const int* __restrict__ cols,
                                            const int* __restrict__ deg,
                                            const float* __restrict__ dinv,
                                            const float* __restrict__ X,
                                            unsigned short* __restrict__ Yh,
                                            unsigned short* __restrict__ Yl) {
    int wave = threadIdx.x >> 6;
    int lane = threadIdx.x & 63;
    int row = blockIdx.x * 4 + wave;
    if (row >= NN) return;
    int d = deg[row];
    float di = dinv[row];
    const int* crow = cols + (size_t)row * MAXDEG;
    const float4* Xv = (const float4*)X;
    float4 xs = Xv[(size_t)row * 64 + lane];
    float4 acc0 = make_float4(di * xs.x, di * xs.y, di * xs.z, di * xs.w);
    float4 acc1 = make_float4(0.f, 0.f, 0.f, 0.f);
    int j = 0;
    for (; j + 1 < d; j += 2) {
        int c0 = crow[j], c1 = crow[j + 1];
        float w0 = dinv[c0], w1 = dinv[c1];
        float4 x0 = Xv[(size_t)c0 * 64 + lane];
        float4 x1 = Xv[(size_t)c1 * 64 + lane];
        acc0.x = fmaf(w0, x0.x, acc0.x); acc1.x = fmaf(w1, x1.x, acc1.x);
        acc0.y = fmaf(w0, x0.y, acc0.y); acc1.y = fmaf(w1, x1.y, acc1.y);
        acc0.z = fmaf(w0, x0.z, acc0.z); acc1.z = fmaf(w1, x1.z, acc1.z);
        acc0.w = fmaf(w0, x0.w, acc0.w); acc1.w = fmaf(w1, x1.w, acc1.w);
    }
    if (j < d) {
        int c0 = crow[j];
        float w0 = dinv[c0];
        float4 x0 = Xv[(size_t)c0 * 64 + lane];
        acc0.x = fmaf(w0, x0.x, acc0.x);
        acc0.y = fmaf(w0, x0.y, acc0.y);
        acc0.z = fmaf(w0, x0.z, acc0.z);
        acc0.w = fmaf(w0, x0.w, acc0.w);
    }
    float4 o = make_float4(di * (acc0.x + acc1.x), di * (acc0.y + acc1.y),
                           di * (acc0.z + acc1.z), di * (acc0.w + acc1.w));
    ushort4 h, l;
    h.x = bf16_rne(o.x); l.x = bf16_rne(o.x - bf16_f32(h.x));
    h.y = bf16_rne(o.y); l.y = bf16_rne(o.y - bf16_f32(h.y));
    h.z = bf16_rne(o.z); l.z = bf16_rne(o.z - bf16_f32(h.z));
    h.w = bf16_rne(o.w); l.w = bf16_rne(o.w - bf16_f32(h.w));
    ((ushort4*)Yh)[(size_t)row * 64 + lane] = h;
    ((ushort4*)Yl)[(size_t)row * 64 + lane] = l;
}

// ---------------------------------------------------------------------------
extern "C" void kernel_launch(void* const* d_in, const int* in_sizes, int n_in,
                              void* d_out, int out_size, void* d_ws, size_t ws_size,
                              hipStream_t stream) {
    const float* x      = (const float*)d_in[0];
    const float* A      = (const float*)d_in[1];
    const float* enc_w  = (const float*)d_in[2];
    const float* enc_b  = (const float*)d_in[3];
    const float* conv_w = (const float*)d_in[4];
    const float* dec_w  = (const float*)d_in[5];
    const float* dec_b  = (const float*)d_in[6];
    float* out = (float*)d_out;

    char* w = (char*)d_ws;
    auto alloc = [&](size_t bytes) {
        char* p = w;
        w += (bytes + 255) & ~(size_t)255;
        return p;
    };
    int*            cols = (int*)alloc((size_t)NN * MAXDEG * 4);
    int*            deg  = (int*)alloc((size_t)NN * 4);
    float*          dinv = (float*)alloc((size_t)NN * 4);
    unsigned short* xh   = (unsigned short*)alloc((size_t)NN * NFEAT * 2);
    unsigned short* xl   = (unsigned short*)alloc((size_t)NN * NFEAT * 2);
    unsigned short* PEh  = (unsigned short*)alloc((size_t)NFEAT * NHID * 2);
    unsigned short* PEl  = (unsigned short*)alloc((size_t)NFEAT * NHID * 2);
    unsigned short* PWh  = (unsigned short*)alloc((size_t)NHID * NHID * 2);
    unsigned short* PWl  = (unsigned short*)alloc((size_t)NHID * NHID * 2);
    unsigned short* PDh  = (unsigned short*)alloc((size_t)NHID * 48 * 2);
    unsigned short* PDl  = (unsigned short*)alloc((size_t)NHID * 48 * 2);
    float*          Xa   = (float*)alloc((size_t)NN * NHID * 4);
    float*          Xb   = (float*)alloc((size_t)NN * NHID * 4);
    unsigned short* Yh   = (unsigned short*)alloc((size_t)NN * NHID * 2);
    unsigned short* Yl   = (unsigned short*)alloc((size_t)NN * NHID * 2);
    unsigned short* Xfh  = (unsigned short*)alloc((size_t)NN * NHID * 2);
    unsigned short* Xfl  = (unsigned short*)alloc((size_t)NN * NHID * 2);

    prep<<<5856, 256, 0, stream>>>(enc_w, conv_w, dec_w, x,
                                   PEh, PEl, PWh, PWl, PDh, PDl, xh, xl, deg);
    scan_upper<<<(NN + 3) / 4, 256, 0, stream>>>(A, cols, deg);
    finalize<<<(NN + 255) / 256, 256, 0, stream>>>(deg, dinv);

    dim3 g4((NN + 63) / 64, 4);
    // encoder: X = relu(x @ enc_w^T + b), K=512, N=256
    mfma_gemm<NFEAT, 16, 4, 0><<<g4, 256, 0, stream>>>(xh, xl, PEh, PEl, enc_b, Xa,
                                                       nullptr, nullptr, 0);
    float* Xcur = Xa;
    float* Xnxt = Xb;
    for (int layer = 0; layer < 4; ++layer) {
        spmm<<<(NN + 3) / 4, 256, 0, stream>>>(cols, deg, dinv, Xcur, Yh, Yl);
        mfma_gemm<NHID, 16, 4, 1><<<g4, 256, 0, stream>>>(Yh, Yl, PWh, PWl, Xcur, Xnxt,
                                                          Xfh, Xfl, layer == 3 ? 1 : 0);
        float* t = Xcur; Xcur = Xnxt; Xnxt = t;
    }
    dim3 g1((NN + 63) / 64, 1);
    mfma_gemm<NHID, 3, 3, 2><<<g1, 256, 0, stream>>>(Xfh, Xfl, PDh, PDl, dec_b, out,
                                                     nullptr, nullptr, 0);
}

// Round 7
// 688.333 us; speedup vs baseline: 1.6715x; 1.0155x over previous
//
#include <hip/hip_runtime.h>
#include <math.h>

#define NN 10000
#define NFEAT 512
#define NHID 256
#define NCLASS 40
#define MAXDEG 64

typedef __attribute__((ext_vector_type(8))) short short8v;   // 8 bf16 (4 VGPR)
typedef __attribute__((ext_vector_type(4))) float floatx4;   // MFMA acc

static __device__ __forceinline__ unsigned short bf16_rne(float f) {
    unsigned u = __builtin_bit_cast(unsigned, f);
    u += 0x7fffu + ((u >> 16) & 1u);
    return (unsigned short)(u >> 16);
}
static __device__ __forceinline__ float bf16_f32(unsigned short h) {
    unsigned u = ((unsigned)h) << 16;
    return __builtin_bit_cast(float, u);
}

// ---------------------------------------------------------------------------
// prep: fused one-shot setup (packs + x split + deg zero). Layout:
//   P[((ks*NTOT+ct)*64+lane)*8+j] = B[k][c],
//   k = ks*32 + 8*(lane>>4) + j,  c = ct*16 + (lane&15)
// ---------------------------------------------------------------------------
__global__ __launch_bounds__(256) void prep(const float* __restrict__ EW,
                                            const float* __restrict__ W,
                                            const float* __restrict__ DW,
                                            const float* __restrict__ x,
                                            unsigned short* __restrict__ PEh,
                                            unsigned short* __restrict__ PEl,
                                            unsigned short* __restrict__ PWh,
                                            unsigned short* __restrict__ PWl,
                                            unsigned short* __restrict__ PDh,
                                            unsigned short* __restrict__ PDl,
                                            unsigned short* __restrict__ xh,
                                            unsigned short* __restrict__ xl,
                                            int* __restrict__ deg) {
    int b = blockIdx.x;
    if (b < 512) {                                  // enc pack
        int idx = b * 256 + threadIdx.x;
        int j = idx & 7, lane = (idx >> 3) & 63;
        int ctks = idx >> 9;
        int ct = ctks & 15, ks = ctks >> 4;
        int k = ks * 32 + ((lane >> 4) << 3) + j;
        int c = ct * 16 + (lane & 15);
        float w = EW[(size_t)c * NFEAT + k];
        unsigned short h = bf16_rne(w);
        PEh[idx] = h;
        PEl[idx] = bf16_rne(w - bf16_f32(h));
    } else if (b < 768) {                           // layer pack (0.25*(W+W^T))
        int idx = (b - 512) * 256 + threadIdx.x;
        int j = idx & 7, lane = (idx >> 3) & 63;
        int ctks = idx >> 9;
        int ct = ctks & 15, ks = ctks >> 4;
        int k = ks * 32 + ((lane >> 4) << 3) + j;
        int c = ct * 16 + (lane & 15);
        float w = 0.25f * (W[k * NHID + c] + W[c * NHID + k]);
        unsigned short h = bf16_rne(w);
        PWh[idx] = h;
        PWl[idx] = bf16_rne(w - bf16_f32(h));
    } else if (b < 816) {                           // dec pack
        int idx = (b - 768) * 256 + threadIdx.x;    // 12288
        int j = idx & 7, lane = (idx >> 3) & 63;
        int ctks = idx >> 9;
        int ct = ctks % 3, ks = ctks / 3;
        int k = ks * 32 + ((lane >> 4) << 3) + j;
        int c = ct * 16 + (lane & 15);
        float w = (c < NCLASS) ? DW[(size_t)c * NHID + k] : 0.f;
        unsigned short h = bf16_rne(w);
        PDh[idx] = h;
        PDl[idx] = bf16_rne(w - bf16_f32(h));
    } else if (b < 5816) {                          // split x (f32 -> bf16 hi/lo)
        int i = (b - 816) * 256 + threadIdx.x;      // 1,280,000 float4
        float4 v = ((const float4*)x)[i];
        ushort4 h, l;
        h.x = bf16_rne(v.x); l.x = bf16_rne(v.x - bf16_f32(h.x));
        h.y = bf16_rne(v.y); l.y = bf16_rne(v.y - bf16_f32(h.y));
        h.z = bf16_rne(v.z); l.z = bf16_rne(v.z - bf16_f32(h.z));
        h.w = bf16_rne(v.w); l.w = bf16_rne(v.w - bf16_f32(h.w));
        ((ushort4*)xh)[i] = h;
        ((ushort4*)xl)[i] = l;
    } else {                                        // zero deg
        int i = (b - 5816) * 256 + threadIdx.x;
        if (i < NN) deg[i] = 0;
    }
}

// ---------------------------------------------------------------------------
// scan_upper: symmetric A -> scan j > i only (200 MB), mirror edges via
// atomic index reservation.
// ---------------------------------------------------------------------------
__global__ __launch_bounds__(256) void scan_upper(const float* __restrict__ A,
                                                  int* __restrict__ cols,
                                                  int* __restrict__ deg) {
    int wave = threadIdx.x >> 6;
    int lane = threadIdx.x & 63;
    int row = blockIdx.x * 4 + wave;
    if (row >= NN) return;
    const float4* Arow = (const float4*)(A + (size_t)row * NN);
    int qstart = (row + 1) >> 2;
    for (int q = qstart + lane; q < NN / 4; q += 64) {
        float4 v = Arow[q];
        int jb = 4 * q;
        if (v.x != 0.f && jb + 0 > row) {
            int p = atomicAdd(&deg[row], 1); if (p < MAXDEG) cols[(size_t)row * MAXDEG + p] = jb;
            int m = atomicAdd(&deg[jb], 1);  if (m < MAXDEG) cols[(size_t)jb * MAXDEG + m] = row;
        }
        if (v.y != 0.f && jb + 1 > row) {
            int j = jb + 1;
            int p = atomicAdd(&deg[row], 1); if (p < MAXDEG) cols[(size_t)row * MAXDEG + p] = j;
            int m = atomicAdd(&deg[j], 1);   if (m < MAXDEG) cols[(size_t)j * MAXDEG + m] = row;
        }
        if (v.z != 0.f && jb + 2 > row) {
            int j = jb + 2;
            int p = atomicAdd(&deg[row], 1); if (p < MAXDEG) cols[(size_t)row * MAXDEG + p] = j;
            int m = atomicAdd(&deg[j], 1);   if (m < MAXDEG) cols[(size_t)j * MAXDEG + m] = row;
        }
        if (v.w != 0.f && jb + 3 > row) {
            int j = jb + 3;
            int p = atomicAdd(&deg[row], 1); if (p < MAXDEG) cols[(size_t)row * MAXDEG + p] = j;
            int m = atomicAdd(&deg[j], 1);   if (m < MAXDEG) cols[(size_t)j * MAXDEG + m] = row;
        }
    }
}

// finalize: dinv from full degree; clamp deg for the gather loop.
__global__ __launch_bounds__(256) void finalize(int* __restrict__ deg,
                                                float* __restrict__ dinv) {
    int i = blockIdx.x * 256 + threadIdx.x;
    if (i >= NN) return;
    int d = deg[i];
    dinv[i] = 1.0f / sqrtf((float)(d + 1));
    deg[i] = d < MAXDEG ? d : MAXDEG;
}

// ---------------------------------------------------------------------------
// MFMA GEMM (bf16x3): used for enc (EPI=0) and dec (EPI=2). r6-verified.
// ---------------------------------------------------------------------------
template <int K, int NTOT, int NT, int EPI>
__global__ __launch_bounds__(256) void mfma_gemm(const unsigned short* __restrict__ Ah,
                                                 const unsigned short* __restrict__ Al,
                                                 const unsigned short* __restrict__ Ph,
                                                 const unsigned short* __restrict__ Pl,
                                                 const float* __restrict__ aux,
                                                 float* __restrict__ out) {
    int tid = threadIdx.x;
    int wave = tid >> 6, lane = tid & 63;
    int rowA = blockIdx.x * 64 + wave * 16 + (lane & 15);
    if (rowA >= NN) rowA = NN - 1;
    int ct0 = blockIdx.y * NT;
    int koff = (lane >> 4) << 3;

    floatx4 acc[NT];
#pragma unroll
    for (int t = 0; t < NT; ++t) acc[t] = (floatx4){0.f, 0.f, 0.f, 0.f};

#pragma unroll
    for (int ks = 0; ks < K / 32; ++ks) {
        short8v a_h = *(const short8v*)(Ah + (size_t)rowA * K + ks * 32 + koff);
        short8v a_l = *(const short8v*)(Al + (size_t)rowA * K + ks * 32 + koff);
        const unsigned short* bph = Ph + ((size_t)(ks * NTOT + ct0) * 64 + lane) * 8;
        const unsigned short* bpl = Pl + ((size_t)(ks * NTOT + ct0) * 64 + lane) * 8;
#pragma unroll
        for (int t = 0; t < NT; ++t) {
            short8v b_h = *(const short8v*)(bph + t * 512);
            short8v b_l = *(const short8v*)(bpl + t * 512);
            acc[t] = __builtin_amdgcn_mfma_f32_16x16x32_bf16(a_h, b_h, acc[t], 0, 0, 0);
            acc[t] = __builtin_amdgcn_mfma_f32_16x16x32_bf16(a_l, b_h, acc[t], 0, 0, 0);
            acc[t] = __builtin_amdgcn_mfma_f32_16x16x32_bf16(a_h, b_l, acc[t], 0, 0, 0);
        }
    }

    int rbase = blockIdx.x * 64 + wave * 16 + ((lane >> 4) << 2);
    int cbase = ct0 * 16 + (lane & 15);
#pragma unroll
    for (int t = 0; t < NT; ++t) {
        int c = cbase + t * 16;
#pragma unroll
        for (int i = 0; i < 4; ++i) {
            int r = rbase + i;
            if (r < NN) {
                float v = acc[t][i];
                if (EPI == 0) {
                    out[(size_t)r * NHID + c] = fmaxf(v + aux[c], 0.f);
                } else {
                    if (c < NCLASS) out[(size_t)r * NCLASS + c] = v + aux[c];
                }
            }
        }
    }
}

// ---------------------------------------------------------------------------
// layer_fused: one kernel = spmm gather (-> LDS) + MFMA GEMM + epilogue.
// Block = 512 threads (8 waves), 32 output rows/block, 313 blocks.
// Phase 1: wave w gathers rows w*4..w*4+3 into LDS Y tile (f32x4, XOR-swizzled
//   chunk index q^(row&7): writes are a chunk permutation (conflict-free),
//   A-frag reads land 2 lanes/bank (free per m136)).
// Phase 2: wave w computes rows (w&1)*16, cols (w>>1)*64 (4 n-frags) with
//   bf16x3 MFMA; A-fragments read from LDS and split in-register.
// Epilogue: Xn = Xc + relu(Xc + acc); last layer also emits bf16 hi/lo split.
// ---------------------------------------------------------------------------
__global__ __launch_bounds__(512) void layer_fused(const int* __restrict__ cols,
                                                   const int* __restrict__ deg,
                                                   const float* __restrict__ dinv,
                                                   const float* __restrict__ Xc,
                                                   const unsigned short* __restrict__ PWh,
                                                   const unsigned short* __restrict__ PWl,
                                                   float* __restrict__ Xn,
                                                   unsigned short* __restrict__ oh,
                                                   unsigned short* __restrict__ ol,
                                                   int wsplit) {
    __shared__ float4 Ylds[32][64];                 // 32 KB, swizzled chunks
    int tid = threadIdx.x, wave = tid >> 6, lane = tid & 63;
    int bx = blockIdx.x;
    const float4* Xv = (const float4*)Xc;

    // ---- phase 1: gather Y rows into LDS ----
#pragma unroll
    for (int rr = 0; rr < 4; ++rr) {
        int lr = wave * 4 + rr;
        int row = bx * 32 + lr;
        if (row < NN) {
            int d = deg[row];
            float di = dinv[row];
            const int* crow = cols + (size_t)row * MAXDEG;
            float4 xs = Xv[(size_t)row * 64 + lane];
            float4 a0 = make_float4(di * xs.x, di * xs.y, di * xs.z, di * xs.w);
            float4 a1 = make_float4(0.f, 0.f, 0.f, 0.f);
            float4 a2 = make_float4(0.f, 0.f, 0.f, 0.f);
            float4 a3 = make_float4(0.f, 0.f, 0.f, 0.f);
            int j = 0;
            for (; j + 3 < d; j += 4) {
                int c0 = crow[j], c1 = crow[j + 1], c2 = crow[j + 2], c3 = crow[j + 3];
                float w0 = dinv[c0], w1 = dinv[c1], w2 = dinv[c2], w3 = dinv[c3];
                float4 x0 = Xv[(size_t)c0 * 64 + lane];
                float4 x1 = Xv[(size_t)c1 * 64 + lane];
                float4 x2 = Xv[(size_t)c2 * 64 + lane];
                float4 x3 = Xv[(size_t)c3 * 64 + lane];
                a0.x = fmaf(w0, x0.x, a0.x); a1.x = fmaf(w1, x1.x, a1.x);
                a2.x = fmaf(w2, x2.x, a2.x); a3.x = fmaf(w3, x3.x, a3.x);
                a0.y = fmaf(w0, x0.y, a0.y); a1.y = fmaf(w1, x1.y, a1.y);
                a2.y = fmaf(w2, x2.y, a2.y); a3.y = fmaf(w3, x3.y, a3.y);
                a0.z = fmaf(w0, x0.z, a0.z); a1.z = fmaf(w1, x1.z, a1.z);
                a2.z = fmaf(w2, x2.z, a2.z); a3.z = fmaf(w3, x3.z, a3.z);
                a0.w = fmaf(w0, x0.w, a0.w); a1.w = fmaf(w1, x1.w, a1.w);
                a2.w = fmaf(w2, x2.w, a2.w); a3.w = fmaf(w3, x3.w, a3.w);
            }
            for (; j < d; ++j) {
                int c0 = crow[j];
                float w0 = dinv[c0];
                float4 x0 = Xv[(size_t)c0 * 64 + lane];
                a0.x = fmaf(w0, x0.x, a0.x);
                a0.y = fmaf(w0, x0.y, a0.y);
                a0.z = fmaf(w0, x0.z, a0.z);
                a0.w = fmaf(w0, x0.w, a0.w);
            }
            float4 o;
            o.x = di * ((a0.x + a1.x) + (a2.x + a3.x));
            o.y = di * ((a0.y + a1.y) + (a2.y + a3.y));
            o.z = di * ((a0.z + a1.z) + (a2.z + a3.z));
            o.w = di * ((a0.w + a1.w) + (a2.w + a3.w));
            Ylds[lr][lane ^ (lr & 7)] = o;
        }
    }
    __syncthreads();

    // ---- phase 2: GEMM 32x256 = Y(32x256) * Wm(256x256), bf16x3 ----
    int wr = wave & 1, wc = wave >> 1;
    floatx4 acc[4];
#pragma unroll
    for (int t = 0; t < 4; ++t) acc[t] = (floatx4){0.f, 0.f, 0.f, 0.f};

#pragma unroll
    for (int ks = 0; ks < 8; ++ks) {
        int lr = wr * 16 + (lane & 15);
        int q = ks * 8 + ((lane >> 4) << 1);
        float4 fa = Ylds[lr][q ^ (lr & 7)];
        float4 fb = Ylds[lr][(q + 1) ^ (lr & 7)];
        float va[8] = {fa.x, fa.y, fa.z, fa.w, fb.x, fb.y, fb.z, fb.w};
        short8v a_h, a_l;
#pragma unroll
        for (int jj = 0; jj < 8; ++jj) {
            unsigned short h = bf16_rne(va[jj]);
            a_h[jj] = (short)h;
            a_l[jj] = (short)bf16_rne(va[jj] - bf16_f32(h));
        }
        const unsigned short* bph = PWh + ((size_t)(ks * 16 + wc * 4) * 64 + lane) * 8;
        const unsigned short* bpl = PWl + ((size_t)(ks * 16 + wc * 4) * 64 + lane) * 8;
#pragma unroll
        for (int t = 0; t < 4; ++t) {
            short8v b_h = *(const short8v*)(bph + t * 512);
            short8v b_l = *(const short8v*)(bpl + t * 512);
            acc[t] = __builtin_amdgcn_mfma_f32_16x16x32_bf16(a_h, b_h, acc[t], 0, 0, 0);
            acc[t] = __builtin_amdgcn_mfma_f32_16x16x32_bf16(a_l, b_h, acc[t], 0, 0, 0);
            acc[t] = __builtin_amdgcn_mfma_f32_16x16x32_bf16(a_h, b_l, acc[t], 0, 0, 0);
        }
    }

    // ---- epilogue ----
    int rb = bx * 32 + wr * 16 + ((lane >> 4) << 2);
    int cb = wc * 64 + (lane & 15);
#pragma unroll
    for (int t = 0; t < 4; ++t) {
        int c = cb + t * 16;
#pragma unroll
        for (int i = 0; i < 4; ++i) {
            int r = rb + i;
            if (r < NN) {
                float v = acc[t][i];
                float xv = Xc[(size_t)r * NHID + c];
                float o = xv + fmaxf(xv + v, 0.f);
                Xn[(size_t)r * NHID + c] = o;
                if (wsplit) {
                    unsigned short h = bf16_rne(o);
                    oh[(size_t)r * NHID + c] = h;
                    ol[(size_t)r * NHID + c] = bf16_rne(o - bf16_f32(h));
                }
            }
        }
    }
}

// ---------------------------------------------------------------------------
extern "C" void kernel_launch(void* const* d_in, const int* in_sizes, int n_in,
                              void* d_out, int out_size, void* d_ws, size_t ws_size,
                              hipStream_t stream) {
    const float* x      = (const float*)d_in[0];
    const float* A      = (const float*)d_in[1];
    const float* enc_w  = (const float*)d_in[2];
    const float* enc_b  = (const float*)d_in[3];
    const float* conv_w = (const float*)d_in[4];
    const float* dec_w  = (const float*)d_in[5];
    const float* dec_b  = (const float*)d_in[6];
    float* out = (float*)d_out;

    char* w = (char*)d_ws;
    auto alloc = [&](size_t bytes) {
        char* p = w;
        w += (bytes + 255) & ~(size_t)255;
        return p;
    };
    int*            cols = (int*)alloc((size_t)NN * MAXDEG * 4);
    int*            deg  = (int*)alloc((size_t)NN * 4);
    float*          dinv = (float*)alloc((size_t)NN * 4);
    unsigned short* xh   = (unsigned short*)alloc((size_t)NN * NFEAT * 2);
    unsigned short* xl   = (unsigned short*)alloc((size_t)NN * NFEAT * 2);
    unsigned short* PEh  = (unsigned short*)alloc((size_t)NFEAT * NHID * 2);
    unsigned short* PEl  = (unsigned short*)alloc((size_t)NFEAT * NHID * 2);
    unsigned short* PWh  = (unsigned short*)alloc((size_t)NHID * NHID * 2);
    unsigned short* PWl  = (unsigned short*)alloc((size_t)NHID * NHID * 2);
    unsigned short* PDh  = (unsigned short*)alloc((size_t)NHID * 48 * 2);
    unsigned short* PDl  = (unsigned short*)alloc((size_t)NHID * 48 * 2);
    float*          Xa   = (float*)alloc((size_t)NN * NHID * 4);
    float*          Xb   = (float*)alloc((size_t)NN * NHID * 4);
    unsigned short* Xfh  = (unsigned short*)alloc((size_t)NN * NHID * 2);
    unsigned short* Xfl  = (unsigned short*)alloc((size_t)NN * NHID * 2);

    prep<<<5856, 256, 0, stream>>>(enc_w, conv_w, dec_w, x,
                                   PEh, PEl, PWh, PWl, PDh, PDl, xh, xl, deg);
    scan_upper<<<(NN + 3) / 4, 256, 0, stream>>>(A, cols, deg);
    finalize<<<(NN + 255) / 256, 256, 0, stream>>>(deg, dinv);

    dim3 g4((NN + 63) / 64, 4);
    mfma_gemm<NFEAT, 16, 4, 0><<<g4, 256, 0, stream>>>(xh, xl, PEh, PEl, enc_b, Xa);

    float* Xcur = Xa;
    float* Xnxt = Xb;
    for (int layer = 0; layer < 4; ++layer) {
        layer_fused<<<(NN + 31) / 32, 512, 0, stream>>>(cols, deg, dinv, Xcur,
                                                        PWh, PWl, Xnxt,
                                                        Xfh, Xfl, layer == 3 ? 1 : 0);
        float* t = Xcur; Xcur = Xnxt; Xnxt = t;
    }
    dim3 g1((NN + 63) / 64, 1);
    mfma_gemm<NHID, 3, 3, 2><<<g1, 256, 0, stream>>>(Xfh, Xfl, PDh, PDl, dec_b, out);
}